// Round 1
// baseline (6259.895 us; speedup 1.0000x reference)
//
#include <hip/hip_runtime.h>
#include <math.h>

#define A_DIM 56
#define E_DIM 128
#define XP 134          // x row pitch: 3 + 128 + 3
#define HP 73           // h1T row pitch: 3 + 56 + 3 + slack (odd -> conflict-free)
#define KP 133          // k row pitch (odd -> conflict-free)

// float offsets into smem
#define X_OFF   0
#define H1_OFF  (A_DIM * XP)              // 7504
#define K_OFF   H1_OFF                    // k matrix reuses dead h1T buffer
#define Q_OFF   (H1_OFF + E_DIM * HP)     // 16848
#define QN_OFF  (Q_OFF + 128)             // 16976
#define LG_OFF  (QN_OFF + 128)            // 17104  (8 x 60)
#define DP_OFF  (LG_OFF + 8 * 60)         // 17584  (4 x 60)
#define LAM_OFF (DP_OFF + 4 * 60)         // 17824
#define SMEM_FLOATS (LAM_OFF + 8)         // 17832 floats = 71,328 B -> 2 blocks/CU

__global__ __launch_bounds__(256, 2)
void atlas_fused(const float* __restrict__ x,
                 const float* __restrict__ w_emb,  const float* __restrict__ b_emb,
                 const float* __restrict__ w_atlas,const float* __restrict__ b_atlas,
                 const float* __restrict__ w_k,
                 const float* __restrict__ qn_w,   const float* __restrict__ qn_b,
                 const float* __restrict__ kn_w,   const float* __restrict__ kn_b,
                 const float* __restrict__ lq1,    const float* __restrict__ lk1,
                 const float* __restrict__ lq2,    const float* __restrict__ lk2,
                 float* __restrict__ out)
{
  __shared__ float smem[SMEM_FLOATS];
  const int t = threadIdx.x;
  const int b = blockIdx.x;

  // ---- Phase 0: zero h1T (incl. pads), stage x[b] into LDS with halo pads,
  //      thread 0 computes lambda_full.
  for (int i = t; i < E_DIM * HP; i += 256) smem[H1_OFF + i] = 0.f;
  {
    const float* xb = x + (size_t)b * (A_DIM * E_DIM);
    for (int i = t; i < A_DIM * XP; i += 256) {
      int row = i / XP, col = i - row * XP;
      int e = col - 3;
      float v = (e >= 0 && e < E_DIM) ? xb[row * E_DIM + e] : 0.f;
      smem[X_OFF + i] = v;
    }
  }
  if (t == 0) {
    float s1 = 0.f, s2 = 0.f;
    for (int i = 0; i < 16; ++i) { s1 += lq1[i] * lk1[i]; s2 += lq2[i] * lk2[i]; }
    smem[LAM_OFF] = expf(s1) - expf(s2) + 0.7f;
  }
  __syncthreads();

  // ---- Phase 1: conv1 over E (mix atlas channels) + SiLU -> h1T[e][3+a]
  // thread: e = t&127, a-range = 28 per half. Weights via uniform scalar loads.
  {
    const int e  = t & 127;
    const int a0 = __builtin_amdgcn_readfirstlane(t >> 7) * 28;
    float acc[28];
#pragma unroll
    for (int j = 0; j < 28; ++j) acc[j] = b_emb[a0 + j];
    for (int ci = 0; ci < A_DIM; ++ci) {
      float xv[7];
#pragma unroll
      for (int k = 0; k < 7; ++k) xv[k] = smem[X_OFF + ci * XP + e + k];
      const float* wp = w_emb + (a0 * A_DIM + ci) * 7;
#pragma unroll
      for (int j = 0; j < 28; ++j) {
        float s = acc[j];
#pragma unroll
        for (int k = 0; k < 7; ++k) s += wp[j * (A_DIM * 7) + k] * xv[k];
        acc[j] = s;
      }
    }
#pragma unroll
    for (int j = 0; j < 28; ++j) {
      float v = acc[j];
      v = v / (1.f + expf(-v));                      // SiLU
      smem[H1_OFF + e * HP + 3 + a0 + j] = v;
    }
  }
  __syncthreads();

  // ---- Phase 2: conv2 over A (mix embed channels) + SiLU + mean over a -> q[eo]
  // wave handles 32 eo (2 chunks of 16); lane = a.
  {
    const int a  = t & 63;
    const int wv = __builtin_amdgcn_readfirstlane(t >> 6);
    for (int c = 0; c < 2; ++c) {
      const int eo0 = wv * 32 + c * 16;
      float acc[16];
#pragma unroll
      for (int j = 0; j < 16; ++j) acc[j] = b_atlas[eo0 + j];
      for (int ei = 0; ei < E_DIM; ++ei) {
        float hv[7];
#pragma unroll
        for (int k = 0; k < 7; ++k) hv[k] = smem[H1_OFF + ei * HP + a + k];
        const float* wp = w_atlas + (eo0 * E_DIM + ei) * 7;
#pragma unroll
        for (int j = 0; j < 16; ++j) {
          float s = acc[j];
#pragma unroll
          for (int k = 0; k < 7; ++k) s += wp[j * (E_DIM * 7) + k] * hv[k];
          acc[j] = s;
        }
      }
#pragma unroll
      for (int j = 0; j < 16; ++j) {
        float v = acc[j];
        v = v / (1.f + expf(-v));                    // SiLU
        v = (a < A_DIM) ? v : 0.f;                   // mask idle lanes
#pragma unroll
        for (int s = 1; s < 64; s <<= 1) v += __shfl_xor(v, s, 64);
        if (a == 0) smem[Q_OFF + eo0 + j] = v * (1.f / 56.f);
      }
    }
  }
  __syncthreads();

  // ---- Phase 3a: layernorm(q) per head-of-16 -> qn (includes *SCALING)
  if (t < 128) {
    float v = smem[Q_OFF + t];
    float s = v;
#pragma unroll
    for (int m = 1; m < 16; m <<= 1) s += __shfl_xor(s, m, 64);
    float mean = s * (1.f / 16.f);
    float d = v - mean;
    float s2 = d * d;
#pragma unroll
    for (int m = 1; m < 16; m <<= 1) s2 += __shfl_xor(s2, m, 64);
    float var = s2 * (1.f / 16.f);
    int dd = t & 15;
    float qn = d * rsqrtf(var + 1e-5f) * qn_w[dd] + qn_b[dd];
    smem[QN_OFF + t] = qn * 0.25f;                   // SCALING = 16^-0.5
  }

  // ---- Phase 3b: k = x @ w_k^T into k_lds (reuses h1T space).
  // lane = a; wave handles 32 o (2 chunks of 16); weights scalar-loaded.
  {
    const int a  = min(t & 63, A_DIM - 1);
    const int wv = __builtin_amdgcn_readfirstlane(t >> 6);
    for (int c = 0; c < 2; ++c) {
      const int o0 = wv * 32 + c * 16;
      float acc[16];
#pragma unroll
      for (int j = 0; j < 16; ++j) acc[j] = 0.f;
      for (int e8 = 0; e8 < 16; ++e8) {
        float xv[8];
#pragma unroll
        for (int i = 0; i < 8; ++i) xv[i] = smem[X_OFF + a * XP + 3 + e8 * 8 + i];
#pragma unroll
        for (int j = 0; j < 16; ++j) {
          const float* wp = w_k + (o0 + j) * E_DIM + e8 * 8;
          float s = acc[j];
#pragma unroll
          for (int i = 0; i < 8; ++i) s += wp[i] * xv[i];
          acc[j] = s;
        }
      }
      if ((t & 63) < A_DIM) {
#pragma unroll
        for (int j = 0; j < 16; ++j) smem[K_OFF + a * KP + o0 + j] = acc[j];
      }
    }
  }
  __syncthreads();

  // ---- Phase 4: layernorm(k) per (a, head) + logit = qn . kn
  for (int r = 0; r < 2; ++r) {
    int task = t + r * 256;
    if (task < A_DIM * 8) {
      int a = task >> 3, h2 = task & 7;
      float kv[16];
      float s = 0.f;
#pragma unroll
      for (int d = 0; d < 16; ++d) { kv[d] = smem[K_OFF + a * KP + h2 * 16 + d]; s += kv[d]; }
      float mean = s * (1.f / 16.f);
      float s2 = 0.f;
#pragma unroll
      for (int d = 0; d < 16; ++d) { float dd = kv[d] - mean; s2 += dd * dd; }
      float rs = rsqrtf(s2 * (1.f / 16.f) + 1e-5f);
      float logit = 0.f;
#pragma unroll
      for (int d = 0; d < 16; ++d) {
        float kn = (kv[d] - mean) * rs * kn_w[d] + kn_b[d];
        logit += smem[QN_OFF + h2 * 16 + d] * kn;
      }
      smem[LG_OFF + h2 * 60 + a] = logit;
    }
  }
  __syncthreads();

  // ---- Phase 5: softmax over a within each of 8 heads (32 threads/head)
  {
    int g = t >> 5;                 // head h2
    int l = t & 31;
    float v0 = smem[LG_OFF + g * 60 + l];
    bool has1 = (l < A_DIM - 32);   // l < 24
    float v1 = has1 ? smem[LG_OFF + g * 60 + 32 + l] : -1e30f;
    float m = fmaxf(v0, v1);
#pragma unroll
    for (int s = 1; s < 32; s <<= 1) m = fmaxf(m, __shfl_xor(m, s, 64));
    float e0 = expf(v0 - m);
    float e1 = has1 ? expf(v1 - m) : 0.f;
    float ssum = e0 + e1;
#pragma unroll
    for (int s = 1; s < 32; s <<= 1) ssum += __shfl_xor(ssum, s, 64);
    float inv = 1.f / ssum;
    smem[LG_OFF + g * 60 + l] = e0 * inv;
    if (has1) smem[LG_OFF + g * 60 + 32 + l] = e1 * inv;
  }
  __syncthreads();

  // ---- Phase 6: diff = p[2h] - lambda*p[2h+1], softmax over a, per h (wave/h)
  {
    int h = t >> 6;
    int a = t & 63;
    float lam = smem[LAM_OFF];
    float dlog = -1e30f;
    if (a < A_DIM) {
      float p0 = smem[LG_OFF + (2 * h) * 60 + a];
      float p1 = smem[LG_OFF + (2 * h + 1) * 60 + a];
      dlog = p0 - lam * p1;
    }
    float m = dlog;
#pragma unroll
    for (int s = 1; s < 64; s <<= 1) m = fmaxf(m, __shfl_xor(m, s, 64));
    float e = (a < A_DIM) ? expf(dlog - m) : 0.f;
    float ss = e;
#pragma unroll
    for (int s = 1; s < 64; s <<= 1) ss += __shfl_xor(ss, s, 64);
    if (a < A_DIM) smem[DP_OFF + h * 60 + a] = e / ss;
  }
  __syncthreads();

  // ---- Phase 7: mean over 4 heads -> out[b, a]
  if (t < A_DIM) {
    float r = 0.25f * (smem[DP_OFF + t] + smem[DP_OFF + 60 + t] +
                       smem[DP_OFF + 120 + t] + smem[DP_OFF + 180 + t]);
    out[(size_t)b * A_DIM + t] = r;
  }
}

extern "C" void kernel_launch(void* const* d_in, const int* in_sizes, int n_in,
                              void* d_out, int out_size, void* d_ws, size_t ws_size,
                              hipStream_t stream) {
  const float* x       = (const float*)d_in[0];
  const float* w_emb   = (const float*)d_in[1];
  const float* b_emb   = (const float*)d_in[2];
  const float* w_atlas = (const float*)d_in[3];
  const float* b_atlas = (const float*)d_in[4];
  const float* w_k     = (const float*)d_in[5];
  const float* qn_w    = (const float*)d_in[6];
  const float* qn_b    = (const float*)d_in[7];
  const float* kn_w    = (const float*)d_in[8];
  const float* kn_b    = (const float*)d_in[9];
  const float* lq1     = (const float*)d_in[10];
  const float* lk1     = (const float*)d_in[11];
  const float* lq2     = (const float*)d_in[12];
  const float* lk2     = (const float*)d_in[13];
  float* out = (float*)d_out;

  const int Bn = in_sizes[0] / (A_DIM * E_DIM);   // 8192
  atlas_fused<<<dim3(Bn), dim3(256), 0, stream>>>(
      x, w_emb, b_emb, w_atlas, b_atlas, w_k,
      qn_w, qn_b, kn_w, kn_b, lq1, lk1, lq2, lk2, out);
}

// Round 2
// 2589.164 us; speedup vs baseline: 2.4177x; 2.4177x over previous
//
#include <hip/hip_runtime.h>
#include <math.h>

#define A_DIM 56
#define E_DIM 128

// ---- LDS layout (float offsets) ----
#define XP      136                    // x row pitch: 4 halo + 128 + 4
#define XS_OFF  0
#define XS_SZ   (A_DIM * XP)           // 7616
#define HP2     64                     // h1T row: cols 0..61 used (a+k), zero-padded
#define H1_OFF  7616
#define H1_SZ   (E_DIM * HP2)          // 8192
#define KM_OFF  H1_OFF                 // k matrix overlays dead h1T
#define KP2     132
#define Q_OFF   15808
#define QN_OFF  15936
#define QP_OFF  16064                  // 4 x 64 partial q sums
#define LG_OFF  16320                  // 8 x 60
#define DP_OFF  16800                  // 4 x 60
#define LAM_OFF 17040
#define SMEM_FLOATS 17048              // 68,192 B -> 2 blocks/CU

// ---- workspace layout (float offsets) ----
#define WEMBT_OFF 0                    // [ci(56)][k(7)][a(64 pad)] = 25088
#define WATT_OFF  25088                // [ei(128)][k(7)][eo(128)]  = 114688
#define WKT_OFF   139776               // [e4(32)][o(128)][4]       = 16384
#define PREP_TOTAL 156160              // floats -> 624,640 B of d_ws

__global__ void prep_weights(const float* __restrict__ w_emb,
                             const float* __restrict__ w_atlas,
                             const float* __restrict__ w_k,
                             float* __restrict__ ws) {
  int idx = blockIdx.x * 256 + threadIdx.x;
  if (idx < 25088) {
    int a = idx & 63, rest = idx >> 6;
    int k = rest % 7, ci = rest / 7;
    ws[WEMBT_OFF + idx] = (a < A_DIM) ? w_emb[(a * A_DIM + ci) * 7 + k] : 0.f;
  } else if (idx < 139776) {
    int o = idx - 25088;
    int eo = o & 127, rest = o >> 7;
    int k = rest % 7, ei = rest / 7;
    ws[WATT_OFF + o] = w_atlas[(eo * E_DIM + ei) * 7 + k];
  } else if (idx < PREP_TOTAL) {
    int o = idx - 139776;
    int r = o & 3, oo = (o >> 2) & 127, e4 = o >> 9;
    ws[WKT_OFF + o] = w_k[oo * E_DIM + e4 * 4 + r];
  }
}

__global__ __launch_bounds__(256, 2)
void atlas_fused(const float* __restrict__ x,
                 const float* __restrict__ ws,
                 const float* __restrict__ b_emb, const float* __restrict__ b_atlas,
                 const float* __restrict__ qn_w,  const float* __restrict__ qn_b,
                 const float* __restrict__ kn_w,  const float* __restrict__ kn_b,
                 const float* __restrict__ lq1,   const float* __restrict__ lk1,
                 const float* __restrict__ lq2,   const float* __restrict__ lk2,
                 float* __restrict__ out)
{
  __shared__ float smem[SMEM_FLOATS];
  const int t = threadIdx.x;
  const int b = blockIdx.x;
  const int lane = t & 63;
  const int w = __builtin_amdgcn_readfirstlane(t >> 6);

  // ---- Phase 0: zero h1T, stage x[b] with 4-col halos, lambda ----
  for (int i = t; i < H1_SZ; i += 256) smem[H1_OFF + i] = 0.f;
  {
    const float* xb = x + (size_t)b * (A_DIM * E_DIM);
    for (int i = t; i < XS_SZ; i += 256) {
      int row = i / XP, col = i - row * XP;
      int e = col - 4;
      smem[XS_OFF + i] = (e >= 0 && e < E_DIM) ? xb[row * E_DIM + e] : 0.f;
    }
  }
  if (t == 0) {
    float s1 = 0.f, s2 = 0.f;
    for (int i = 0; i < 16; ++i) { s1 += lq1[i] * lk1[i]; s2 += lq2[i] * lk2[i]; }
    smem[LAM_OFF] = expf(s1) - expf(s2) + 0.7f;
  }
  __syncthreads();

  // ---- Phase 1: conv1 + SiLU -> h1T[e][3+a]. lane=a, wave owns e in [32w,32w+32)
  {
    const int e0 = w * 32;
    const float* wemb = ws + WEMBT_OFF;
    float be = (lane < A_DIM) ? b_emb[lane] : 0.f;
    float acc[32];
#pragma unroll
    for (int j = 0; j < 32; ++j) acc[j] = be;
    float wv[7];
#pragma unroll
    for (int k = 0; k < 7; ++k) wv[k] = wemb[k * 64 + lane];   // ci = 0
    for (int ci = 0; ci < A_DIM; ++ci) {
      float wn[7] = {0.f, 0.f, 0.f, 0.f, 0.f, 0.f, 0.f};
      if (ci + 1 < A_DIM) {
#pragma unroll
        for (int k = 0; k < 7; ++k) wn[k] = wemb[((ci + 1) * 7 + k) * 64 + lane];
      }
      // broadcast x window: cols e0 .. e0+39 (need e0+1 .. e0+38)
      float xw[40];
      const float4* xr = (const float4*)&smem[XS_OFF + ci * XP + e0];
#pragma unroll
      for (int i = 0; i < 10; ++i) {
        float4 v = xr[i];
        xw[4*i] = v.x; xw[4*i+1] = v.y; xw[4*i+2] = v.z; xw[4*i+3] = v.w;
      }
#pragma unroll
      for (int k = 0; k < 7; ++k)
#pragma unroll
        for (int j = 0; j < 32; ++j)
          acc[j] = fmaf(wv[k], xw[j + k + 1], acc[j]);
#pragma unroll
      for (int k = 0; k < 7; ++k) wv[k] = wn[k];
    }
    if (lane < A_DIM) {
#pragma unroll
      for (int j = 0; j < 32; ++j) {
        float v = acc[j];
        v = v / (1.f + expf(-v));                      // SiLU
        smem[H1_OFF + (e0 + j) * HP2 + 3 + lane] = v;
      }
    }
  }
  __syncthreads();

  // ---- Phase 2: conv2 + SiLU + mean over a. lane=eo-half, wave-pair owns 28 a's
  {
    const int a0 = (w >> 1) * 28;
    const int eo = (w & 1) * 64 + lane;
    const float* wat = ws + WATT_OFF;
    float acc[28];
    float ba = b_atlas[eo];
#pragma unroll
    for (int j = 0; j < 28; ++j) acc[j] = ba;
    float wv[7];
#pragma unroll
    for (int k = 0; k < 7; ++k) wv[k] = wat[k * 128 + eo];     // ei = 0
    for (int ei = 0; ei < E_DIM; ++ei) {
      float wn[7] = {0.f, 0.f, 0.f, 0.f, 0.f, 0.f, 0.f};
      if (ei + 1 < E_DIM) {
#pragma unroll
        for (int k = 0; k < 7; ++k) wn[k] = wat[((ei + 1) * 7 + k) * 128 + eo];
      }
      // broadcast h window: cols a0 .. a0+35 (need a0 .. a0+34)
      float hw[36];
      const float4* hr = (const float4*)&smem[H1_OFF + ei * HP2 + a0];
#pragma unroll
      for (int i = 0; i < 9; ++i) {
        float4 v = hr[i];
        hw[4*i] = v.x; hw[4*i+1] = v.y; hw[4*i+2] = v.z; hw[4*i+3] = v.w;
      }
#pragma unroll
      for (int k = 0; k < 7; ++k)
#pragma unroll
        for (int j = 0; j < 28; ++j)
          acc[j] = fmaf(wv[k], hw[j + k], acc[j]);
#pragma unroll
      for (int k = 0; k < 7; ++k) wv[k] = wn[k];
    }
    float s = 0.f;
#pragma unroll
    for (int j = 0; j < 28; ++j) {
      float v = acc[j];
      v = v / (1.f + expf(-v));                        // SiLU
      s += v;
    }
    smem[QP_OFF + w * 64 + lane] = s;                  // partial over this a-range
  }
  __syncthreads();

  // combine q partials: q[eo] = (part_a0=0 + part_a0=28) / 56
  if (t < 128) {
    int bsel = t >> 6, l = t & 63;
    smem[Q_OFF + t] = (smem[QP_OFF + bsel * 64 + l] +
                       smem[QP_OFF + (bsel + 2) * 64 + l]) * (1.f / 56.f);
  }
  __syncthreads();

  // ---- Phase 3a: layernorm(q) per head-of-16 (includes *SCALING) ----
  if (t < 128) {
    float v = smem[Q_OFF + t];
    float s = v;
#pragma unroll
    for (int m = 1; m < 16; m <<= 1) s += __shfl_xor(s, m, 64);
    float mean = s * (1.f / 16.f);
    float d = v - mean;
    float s2 = d * d;
#pragma unroll
    for (int m = 1; m < 16; m <<= 1) s2 += __shfl_xor(s2, m, 64);
    float var = s2 * (1.f / 16.f);
    int dd = t & 15;
    float qn = d * rsqrtf(var + 1e-5f) * qn_w[dd] + qn_b[dd];
    smem[QN_OFF + t] = qn * 0.25f;                     // SCALING = 16^-0.5
  }

  // ---- Phase 3b: k = x @ w_k^T -> kmat[a][o] (overlays h1T). lane=o-half, wave owns 14 a's
  {
    const int a0 = w * 14;
    const float* wkt = ws + WKT_OFF;
    float acc0[14], acc1[14];
#pragma unroll
    for (int j = 0; j < 14; ++j) { acc0[j] = 0.f; acc1[j] = 0.f; }
    float4 w0 = *(const float4*)&wkt[(0 * 128 + lane) * 4];
    float4 w1 = *(const float4*)&wkt[(0 * 128 + 64 + lane) * 4];
    for (int e4 = 0; e4 < 32; ++e4) {
      float4 n0 = make_float4(0.f, 0.f, 0.f, 0.f), n1 = n0;
      if (e4 + 1 < 32) {
        n0 = *(const float4*)&wkt[((e4 + 1) * 128 + lane) * 4];
        n1 = *(const float4*)&wkt[((e4 + 1) * 128 + 64 + lane) * 4];
      }
#pragma unroll
      for (int j = 0; j < 14; ++j) {
        const float4 xv = *(const float4*)&smem[XS_OFF + (a0 + j) * XP + 4 + 4 * e4];
        acc0[j] = fmaf(w0.x, xv.x, acc0[j]); acc0[j] = fmaf(w0.y, xv.y, acc0[j]);
        acc0[j] = fmaf(w0.z, xv.z, acc0[j]); acc0[j] = fmaf(w0.w, xv.w, acc0[j]);
        acc1[j] = fmaf(w1.x, xv.x, acc1[j]); acc1[j] = fmaf(w1.y, xv.y, acc1[j]);
        acc1[j] = fmaf(w1.z, xv.z, acc1[j]); acc1[j] = fmaf(w1.w, xv.w, acc1[j]);
      }
      w0 = n0; w1 = n1;
    }
#pragma unroll
    for (int j = 0; j < 14; ++j) {
      smem[KM_OFF + (a0 + j) * KP2 + lane]      = acc0[j];
      smem[KM_OFF + (a0 + j) * KP2 + 64 + lane] = acc1[j];
    }
  }
  __syncthreads();

  // ---- Phase 4: layernorm(k) per (a, head) + logit = qn . kn ----
  for (int r = 0; r < 2; ++r) {
    int task = t + r * 256;
    if (task < A_DIM * 8) {
      int a = task >> 3, h2 = task & 7;
      float kv[16];
      float s = 0.f;
#pragma unroll
      for (int d = 0; d < 16; ++d) { kv[d] = smem[KM_OFF + a * KP2 + h2 * 16 + d]; s += kv[d]; }
      float mean = s * (1.f / 16.f);
      float s2 = 0.f;
#pragma unroll
      for (int d = 0; d < 16; ++d) { float dd = kv[d] - mean; s2 += dd * dd; }
      float rs = rsqrtf(s2 * (1.f / 16.f) + 1e-5f);
      float logit = 0.f;
#pragma unroll
      for (int d = 0; d < 16; ++d) {
        float kn = (kv[d] - mean) * rs * kn_w[d] + kn_b[d];
        logit += smem[QN_OFF + h2 * 16 + d] * kn;
      }
      smem[LG_OFF + h2 * 60 + a] = logit;
    }
  }
  __syncthreads();

  // ---- Phase 5: softmax over a within each of 8 heads (32 threads/head) ----
  {
    int g = t >> 5;
    int l = t & 31;
    float v0 = smem[LG_OFF + g * 60 + l];
    bool has1 = (l < A_DIM - 32);
    float v1 = has1 ? smem[LG_OFF + g * 60 + 32 + l] : -1e30f;
    float m = fmaxf(v0, v1);
#pragma unroll
    for (int s = 1; s < 32; s <<= 1) m = fmaxf(m, __shfl_xor(m, s, 64));
    float e0 = expf(v0 - m);
    float e1 = has1 ? expf(v1 - m) : 0.f;
    float ssum = e0 + e1;
#pragma unroll
    for (int s = 1; s < 32; s <<= 1) ssum += __shfl_xor(ssum, s, 64);
    float inv = 1.f / ssum;
    smem[LG_OFF + g * 60 + l] = e0 * inv;
    if (has1) smem[LG_OFF + g * 60 + 32 + l] = e1 * inv;
  }
  __syncthreads();

  // ---- Phase 6: diff softmax per head h (one wave per h) ----
  {
    int h = t >> 6;
    int a = t & 63;
    float lam = smem[LAM_OFF];
    float dlog = -1e30f;
    if (a < A_DIM) {
      float p0 = smem[LG_OFF + (2 * h) * 60 + a];
      float p1 = smem[LG_OFF + (2 * h + 1) * 60 + a];
      dlog = p0 - lam * p1;
    }
    float m = dlog;
#pragma unroll
    for (int s = 1; s < 64; s <<= 1) m = fmaxf(m, __shfl_xor(m, s, 64));
    float e = (a < A_DIM) ? expf(dlog - m) : 0.f;
    float ss = e;
#pragma unroll
    for (int s = 1; s < 64; s <<= 1) ss += __shfl_xor(ss, s, 64);
    if (a < A_DIM) smem[DP_OFF + h * 60 + a] = e / ss;
  }
  __syncthreads();

  // ---- Phase 7: mean over heads ----
  if (t < A_DIM) {
    float r = 0.25f * (smem[DP_OFF + t] + smem[DP_OFF + 60 + t] +
                       smem[DP_OFF + 120 + t] + smem[DP_OFF + 180 + t]);
    out[(size_t)b * A_DIM + t] = r;
  }
}

extern "C" void kernel_launch(void* const* d_in, const int* in_sizes, int n_in,
                              void* d_out, int out_size, void* d_ws, size_t ws_size,
                              hipStream_t stream) {
  const float* x       = (const float*)d_in[0];
  const float* w_emb   = (const float*)d_in[1];
  const float* b_emb   = (const float*)d_in[2];
  const float* w_atlas = (const float*)d_in[3];
  const float* b_atlas = (const float*)d_in[4];
  const float* w_k     = (const float*)d_in[5];
  const float* qn_w    = (const float*)d_in[6];
  const float* qn_b    = (const float*)d_in[7];
  const float* kn_w    = (const float*)d_in[8];
  const float* kn_b    = (const float*)d_in[9];
  const float* lq1     = (const float*)d_in[10];
  const float* lk1     = (const float*)d_in[11];
  const float* lq2     = (const float*)d_in[12];
  const float* lk2     = (const float*)d_in[13];
  float* out = (float*)d_out;
  float* ws  = (float*)d_ws;

  prep_weights<<<dim3((PREP_TOTAL + 255) / 256), dim3(256), 0, stream>>>(
      w_emb, w_atlas, w_k, ws);

  const int Bn = in_sizes[0] / (A_DIM * E_DIM);   // 8192
  atlas_fused<<<dim3(Bn), dim3(256), 0, stream>>>(
      x, ws, b_emb, b_atlas, qn_w, qn_b, kn_w, kn_b,
      lq1, lk1, lq2, lk2, out);
}

// Round 3
// 2046.394 us; speedup vs baseline: 3.0590x; 1.2652x over previous
//
#include <hip/hip_runtime.h>
#include <math.h>

#define A_DIM 56
#define E_DIM 128

typedef short short8 __attribute__((ext_vector_type(8)));
typedef float floatx4 __attribute__((ext_vector_type(4)));

// ---------------- LDS layout (byte offsets, 16B-aligned) ----------------
// xT: bf16 [134 rows = e+3][pitch 72 (ci, zero-padded past 55)]
#define XT_HI_B 0
#define XT_LO_B 19296
// h:  bf16 [62 rows = a+3][pitch 136 (ei)] ; rows 0-2 and 59-61 are zero pads
#define H_HI_B  38592
#define H_LO_B  55456
// kmat fp32 [56 a][pitch 132 (o)] overlays xT region (dead after conv1)
#define KM_B    0
#define Q_B     72320
#define QN_B    72832
#define LG_B    73344
#define DP_B    75264
#define LAM_B   76224
#define SMEM_B  76240

#define QF   (Q_B/4)
#define QNF  (QN_B/4)
#define LGF  (LG_B/4)
#define DPF  (DP_B/4)
#define LAMF (LAM_B/4)
#define KP2  132

// ---------------- workspace (ushort element offsets) ----------------
#define W1P  0            // [s2][tap7][a64][ci64]   (a>=56 or ci>=56 -> 0)
#define W1S  28672
#define W2P  57344        // [s2][tap7][eo128][ei128]
#define W2S  114688
#define WKP  286720       // [s2][o128][e128]
#define WKS  16384
#define PREP_ELEMS 159744 // 28672 + 114688 + 16384

__device__ __forceinline__ unsigned rne16(unsigned u) {
  return (u + 0x7FFFu + ((u >> 16) & 1u)) >> 16;
}
// pack truncated bf16(hi16) of two fp32 bit-patterns into one dword
__device__ __forceinline__ unsigned pack_hi16(unsigned u0, unsigned u1) {
  return __builtin_amdgcn_perm(u1, u0, 0x07060302u);
}
__device__ __forceinline__ float silu_f(float v) { return v / (1.f + __expf(-v)); }

union Frag { unsigned d[4]; short8 s; };

__global__ void prep_weights(const float* __restrict__ w_emb,
                             const float* __restrict__ w_atlas,
                             const float* __restrict__ w_k,
                             unsigned short* __restrict__ ws) {
  int idx = blockIdx.x * 256 + threadIdx.x;
  float v; int dst_hi, dst_lo;
  if (idx < 28672) {                       // w1p: idx = tap*4096 + a*64 + ci
    int tap = idx >> 12, a = (idx >> 6) & 63, ci = idx & 63;
    v = (a < A_DIM && ci < A_DIM) ? w_emb[(a * A_DIM + ci) * 7 + tap] : 0.f;
    dst_hi = W1P + idx; dst_lo = W1P + W1S + idx;
  } else if (idx < 143360) {               // w2p: j = tap*16384 + eo*128 + ei
    int j = idx - 28672;
    int tap = j >> 14, eo = (j >> 7) & 127, ei = j & 127;
    v = w_atlas[(eo * E_DIM + ei) * 7 + tap];
    dst_hi = W2P + j; dst_lo = W2P + W2S + j;
  } else if (idx < PREP_ELEMS) {           // wkp: j = o*128 + e (w_k already [o][e])
    int j = idx - 143360;
    v = w_k[j];
    dst_hi = WKP + j; dst_lo = WKP + WKS + j;
  } else return;
  unsigned u = __float_as_uint(v);
  unsigned hi = rne16(u);
  float lof = v - __uint_as_float(hi << 16);
  unsigned lo = rne16(__float_as_uint(lof));
  ws[dst_hi] = (unsigned short)hi;
  ws[dst_lo] = (unsigned short)lo;
}

__global__ __launch_bounds__(256, 2)
void atlas_fused(const float* __restrict__ x,
                 const unsigned short* __restrict__ ws,
                 const float* __restrict__ b_emb, const float* __restrict__ b_atlas,
                 const float* __restrict__ qn_w,  const float* __restrict__ qn_b,
                 const float* __restrict__ kn_w,  const float* __restrict__ kn_b,
                 const float* __restrict__ lq1,   const float* __restrict__ lk1,
                 const float* __restrict__ lq2,   const float* __restrict__ lk2,
                 float* __restrict__ out)
{
  __shared__ __align__(16) unsigned char smem[SMEM_B];
  float* smf = (float*)smem;
  const int t = threadIdx.x;
  const int b = blockIdx.x;
  const int lane = t & 63;
  const int w = __builtin_amdgcn_readfirstlane(t >> 6);
  const int lm = lane & 15;            // MFMA m/n index within tile
  const int lk = (lane >> 4) * 8;      // MFMA k-run start within 32-chunk
  const int lr = (lane >> 4) * 4;      // MFMA C row base within tile

  const float* xb = x + (size_t)b * (A_DIM * E_DIM);

  // ================= Phase 0: init LDS, stage x -> xT hi/lo, lambda ========
  {
    uint4 z4 = make_uint4(0, 0, 0, 0);
    for (int i = t; i < 2412; i += 256) ((uint4*)smem)[i] = z4;   // zero xT (38592 B)
    // zero h pad rows {0,1,2,59,60,61} in hi & lo
    for (int i = t; i < 816; i += 256) {
      int arr = i / 408, j = i - arr * 408;
      int r6 = j / 68, c = j - r6 * 68;
      int row = (r6 < 3) ? r6 : 56 + r6;
      *(unsigned*)(smem + (arr ? H_LO_B : H_HI_B) + row * 272 + c * 4) = 0u;
    }
    if (t == 0) {
      float s1 = 0.f, s2 = 0.f;
      for (int i = 0; i < 16; ++i) { s1 += lq1[i] * lk1[i]; s2 += lq2[i] * lk2[i]; }
      smf[LAMF] = expf(s1) - expf(s2) + 0.7f;
    }
  }
  __syncthreads();
  {
    unsigned short* xth = (unsigned short*)(smem + XT_HI_B);
    unsigned short* xtl = (unsigned short*)(smem + XT_LO_B);
    for (int i = t; i < 1792; i += 256) {       // 56 a * 32 float4
      int a = i >> 5, e4 = i & 31;
      float4 v = *(const float4*)(xb + a * 128 + e4 * 4);
      float f[4] = {v.x, v.y, v.z, v.w};
#pragma unroll
      for (int j = 0; j < 4; ++j) {
        int e = e4 * 4 + j;
        unsigned u = __float_as_uint(f[j]);
        xth[(e + 3) * 72 + a] = (unsigned short)(u >> 16);
        float lof = f[j] - __uint_as_float(u & 0xFFFF0000u);
        xtl[(e + 3) * 72 + a] = (unsigned short)(__float_as_uint(lof) >> 16);
      }
    }
  }
  __syncthreads();

  // ================= Phase 1: conv1 (C1^T[e][a]) via MFMA ==================
  // A[m=e][k=ci] = xT ; B[k=ci][n=a] = w1p ; 3 passes x 7 taps x 2 kc
  {
    floatx4 acc[2][4];
    float be[4];
#pragma unroll
    for (int nt = 0; nt < 4; ++nt) {
      int a = nt * 16 + lm;
      be[nt] = (a < A_DIM) ? b_emb[a] : 0.f;
    }
#pragma unroll
    for (int mt = 0; mt < 2; ++mt)
#pragma unroll
      for (int nt = 0; nt < 4; ++nt) {
        acc[mt][nt][0] = be[nt]; acc[mt][nt][1] = be[nt];
        acc[mt][nt][2] = be[nt]; acc[mt][nt][3] = be[nt];
      }
    for (int pass = 0; pass < 3; ++pass) {
      const unsigned short* xsel = (const unsigned short*)(smem + (pass == 1 ? XT_LO_B : XT_HI_B));
      const unsigned short* wsel = ws + W1P + (pass == 2 ? W1S : 0);
      for (int tap = 0; tap < 7; ++tap) {
#pragma unroll
        for (int kc = 0; kc < 2; ++kc) {
          short8 afr[2], bfr[4];
#pragma unroll
          for (int mt = 0; mt < 2; ++mt) {
            int row = 16 * (2 * w + mt) + lm + tap;
            afr[mt] = *(const short8*)(xsel + row * 72 + kc * 32 + lk);
          }
#pragma unroll
          for (int nt = 0; nt < 4; ++nt)
            bfr[nt] = *(const short8*)(wsel + (tap * 64 + 16 * nt + lm) * 64 + kc * 32 + lk);
#pragma unroll
          for (int mt = 0; mt < 2; ++mt)
#pragma unroll
            for (int nt = 0; nt < 4; ++nt)
              acc[mt][nt] = __builtin_amdgcn_mfma_f32_16x16x32_bf16(afr[mt], bfr[nt], acc[mt][nt], 0, 0, 0);
        }
      }
    }
    // epilogue: SiLU, split hi/lo, write h[a+3][e] (4 consecutive e per lane)
#pragma unroll
    for (int mt = 0; mt < 2; ++mt) {
      int e0 = 16 * (2 * w + mt) + lr;
#pragma unroll
      for (int nt = 0; nt < 4; ++nt) {
        int a = 16 * nt + lm;
        if (a < A_DIM) {
          float v0 = silu_f(acc[mt][nt][0]), v1 = silu_f(acc[mt][nt][1]);
          float v2 = silu_f(acc[mt][nt][2]), v3 = silu_f(acc[mt][nt][3]);
          unsigned u0 = __float_as_uint(v0), u1 = __float_as_uint(v1);
          unsigned u2 = __float_as_uint(v2), u3 = __float_as_uint(v3);
          float l0 = v0 - __uint_as_float(u0 & 0xFFFF0000u);
          float l1 = v1 - __uint_as_float(u1 & 0xFFFF0000u);
          float l2 = v2 - __uint_as_float(u2 & 0xFFFF0000u);
          float l3 = v3 - __uint_as_float(u3 & 0xFFFF0000u);
          int off = (a + 3) * 272 + e0 * 2;
          *(uint2*)(smem + H_HI_B + off) = make_uint2(pack_hi16(u0, u1), pack_hi16(u2, u3));
          *(uint2*)(smem + H_LO_B + off) =
              make_uint2(pack_hi16(__float_as_uint(l0), __float_as_uint(l1)),
                         pack_hi16(__float_as_uint(l2), __float_as_uint(l3)));
        }
      }
    }
  }
  __syncthreads();

  // ================= Phase 2: conv2 (C2[eo][a]) + mean over a -> q =========
  // A[m=eo][k=ei] = w2p (global) ; B[k=ei][n=a] = h[a+tap][ei] (LDS)
  {
    floatx4 acc[2][4];
#pragma unroll
    for (int mt = 0; mt < 2; ++mt) {
      float b0 = b_atlas[16 * (2 * w + mt) + lr + 0];
      float b1 = b_atlas[16 * (2 * w + mt) + lr + 1];
      float b2 = b_atlas[16 * (2 * w + mt) + lr + 2];
      float b3 = b_atlas[16 * (2 * w + mt) + lr + 3];
#pragma unroll
      for (int nt = 0; nt < 4; ++nt) {
        acc[mt][nt][0] = b0; acc[mt][nt][1] = b1;
        acc[mt][nt][2] = b2; acc[mt][nt][3] = b3;
      }
    }
    for (int pass = 0; pass < 3; ++pass) {
      const unsigned char* hsel = smem + (pass == 1 ? H_LO_B : H_HI_B);
      const unsigned short* wsel = ws + W2P + (pass == 2 ? W2S : 0);
      for (int tap = 0; tap < 7; ++tap) {
        int rown[4];
#pragma unroll
        for (int nt = 0; nt < 4; ++nt) {
          int r = 16 * nt + lm + tap;
          rown[nt] = (r > 61) ? 61 : r;   // clamp: only affects discarded a>=56 cols
        }
#pragma unroll
        for (int kc = 0; kc < 4; ++kc) {
          short8 afr[2], bfr[4];
#pragma unroll
          for (int mt = 0; mt < 2; ++mt)
            afr[mt] = *(const short8*)(wsel + (tap * 128 + 16 * (2 * w + mt) + lm) * 128 + kc * 32 + lk);
#pragma unroll
          for (int nt = 0; nt < 4; ++nt)
            bfr[nt] = *(const short8*)(hsel + rown[nt] * 272 + (kc * 32 + lk) * 2);
#pragma unroll
          for (int mt = 0; mt < 2; ++mt)
#pragma unroll
            for (int nt = 0; nt < 4; ++nt)
              acc[mt][nt] = __builtin_amdgcn_mfma_f32_16x16x32_bf16(afr[mt], bfr[nt], acc[mt][nt], 0, 0, 0);
        }
      }
    }
    // epilogue: SiLU, mask a<56, reduce over a (16 lanes + 4 nt), q[eo]
#pragma unroll
    for (int mt = 0; mt < 2; ++mt) {
#pragma unroll
      for (int r = 0; r < 4; ++r) {
        float s = 0.f;
#pragma unroll
        for (int nt = 0; nt < 4; ++nt) {
          float v = silu_f(acc[mt][nt][r]);
          int a = 16 * nt + lm;
          s += (a < A_DIM) ? v : 0.f;
        }
        s += __shfl_xor(s, 1, 64);
        s += __shfl_xor(s, 2, 64);
        s += __shfl_xor(s, 4, 64);
        s += __shfl_xor(s, 8, 64);
        if (lm == 0) {
          int eo = 16 * (2 * w + mt) + lr + r;
          smf[QF + eo] = s * (1.f / 56.f);
        }
      }
    }
  }
  __syncthreads();

  // ================= Phase 3a: layernorm(q) per head-of-16 (incl *SCALING) =
  if (t < 128) {
    float v = smf[QF + t];
    float s = v;
#pragma unroll
    for (int m = 1; m < 16; m <<= 1) s += __shfl_xor(s, m, 64);
    float mean = s * (1.f / 16.f);
    float d = v - mean;
    float s2 = d * d;
#pragma unroll
    for (int m = 1; m < 16; m <<= 1) s2 += __shfl_xor(s2, m, 64);
    float var = s2 * (1.f / 16.f);
    int dd = t & 15;
    float qn = d * rsqrtf(var + 1e-5f) * qn_w[dd] + qn_b[dd];
    smf[QNF + t] = qn * 0.25f;
  }

  // ================= Phase 3b: k-proj (C3^T[o][a]) -> kmat[a][o] ===========
  // A[m=o][k=e] = wkp (global) ; B[k=e][n=a] = x (global fp32, split on the fly)
  {
    floatx4 acc[2][4];
#pragma unroll
    for (int mt = 0; mt < 2; ++mt)
#pragma unroll
      for (int nt = 0; nt < 4; ++nt) {
        acc[mt][nt][0] = 0.f; acc[mt][nt][1] = 0.f;
        acc[mt][nt][2] = 0.f; acc[mt][nt][3] = 0.f;
      }
    const unsigned short* wk0 = ws + WKP;
    for (int kc = 0; kc < 4; ++kc) {
      float4 xf[4][2];
#pragma unroll
      for (int nt = 0; nt < 4; ++nt) {
        int a = 16 * nt + lm; a = (a > 55) ? 55 : a;
        const float* p = xb + a * 128 + kc * 32 + lk;
        xf[nt][0] = *(const float4*)p;
        xf[nt][1] = *(const float4*)(p + 4);
      }
      Frag bhi[4];
#pragma unroll
      for (int nt = 0; nt < 4; ++nt) {
        unsigned u0 = __float_as_uint(xf[nt][0].x), u1 = __float_as_uint(xf[nt][0].y);
        unsigned u2 = __float_as_uint(xf[nt][0].z), u3 = __float_as_uint(xf[nt][0].w);
        unsigned u4 = __float_as_uint(xf[nt][1].x), u5 = __float_as_uint(xf[nt][1].y);
        unsigned u6 = __float_as_uint(xf[nt][1].z), u7 = __float_as_uint(xf[nt][1].w);
        bhi[nt].d[0] = pack_hi16(u0, u1); bhi[nt].d[1] = pack_hi16(u2, u3);
        bhi[nt].d[2] = pack_hi16(u4, u5); bhi[nt].d[3] = pack_hi16(u6, u7);
      }
      for (int pass = 0; pass < 3; ++pass) {
        short8 afr[2];
        const unsigned short* wsel = wk0 + (pass == 2 ? WKS : 0);
#pragma unroll
        for (int mt = 0; mt < 2; ++mt)
          afr[mt] = *(const short8*)(wsel + (16 * (2 * w + mt) + lm) * 128 + kc * 32 + lk);
        if (pass == 1) {
          Frag blo[4];
#pragma unroll
          for (int nt = 0; nt < 4; ++nt) {
            float f[8] = {xf[nt][0].x, xf[nt][0].y, xf[nt][0].z, xf[nt][0].w,
                          xf[nt][1].x, xf[nt][1].y, xf[nt][1].z, xf[nt][1].w};
            unsigned lu[8];
#pragma unroll
            for (int j = 0; j < 8; ++j) {
              unsigned u = __float_as_uint(f[j]);
              lu[j] = __float_as_uint(f[j] - __uint_as_float(u & 0xFFFF0000u));
            }
            blo[nt].d[0] = pack_hi16(lu[0], lu[1]); blo[nt].d[1] = pack_hi16(lu[2], lu[3]);
            blo[nt].d[2] = pack_hi16(lu[4], lu[5]); blo[nt].d[3] = pack_hi16(lu[6], lu[7]);
          }
#pragma unroll
          for (int mt = 0; mt < 2; ++mt)
#pragma unroll
            for (int nt = 0; nt < 4; ++nt)
              acc[mt][nt] = __builtin_amdgcn_mfma_f32_16x16x32_bf16(afr[mt], blo[nt].s, acc[mt][nt], 0, 0, 0);
        } else {
#pragma unroll
          for (int mt = 0; mt < 2; ++mt)
#pragma unroll
            for (int nt = 0; nt < 4; ++nt)
              acc[mt][nt] = __builtin_amdgcn_mfma_f32_16x16x32_bf16(afr[mt], bhi[nt].s, acc[mt][nt], 0, 0, 0);
        }
      }
    }
    // epilogue: kmat[a][o0..o0+3] float4 per (mt,nt)
#pragma unroll
    for (int mt = 0; mt < 2; ++mt) {
      int o0 = 16 * (2 * w + mt) + lr;
#pragma unroll
      for (int nt = 0; nt < 4; ++nt) {
        int a = 16 * nt + lm;
        if (a < A_DIM)
          *(floatx4*)&smf[(KM_B / 4) + a * KP2 + o0] = acc[mt][nt];
      }
    }
  }
  __syncthreads();

  // ================= Phase 4: layernorm(k) + logit = qn . kn ===============
  for (int r = 0; r < 2; ++r) {
    int task = t + r * 256;
    if (task < A_DIM * 8) {
      int a = task >> 3, h2 = task & 7;
      float kv[16];
      float s = 0.f;
#pragma unroll
      for (int d = 0; d < 16; ++d) { kv[d] = smf[(KM_B / 4) + a * KP2 + h2 * 16 + d]; s += kv[d]; }
      float mean = s * (1.f / 16.f);
      float s2 = 0.f;
#pragma unroll
      for (int d = 0; d < 16; ++d) { float dd = kv[d] - mean; s2 += dd * dd; }
      float rs = rsqrtf(s2 * (1.f / 16.f) + 1e-5f);
      float logit = 0.f;
#pragma unroll
      for (int d = 0; d < 16; ++d) {
        float kn = (kv[d] - mean) * rs * kn_w[d] + kn_b[d];
        logit += smf[QNF + h2 * 16 + d] * kn;
      }
      smf[LGF + h2 * 60 + a] = logit;
    }
  }
  __syncthreads();

  // ================= Phase 5: softmax over a per head2 =====================
  {
    int g = t >> 5;
    int l = t & 31;
    float v0 = smf[LGF + g * 60 + l];
    bool has1 = (l < A_DIM - 32);
    float v1 = has1 ? smf[LGF + g * 60 + 32 + l] : -1e30f;
    float m = fmaxf(v0, v1);
#pragma unroll
    for (int s = 1; s < 32; s <<= 1) m = fmaxf(m, __shfl_xor(m, s, 64));
    float e0 = expf(v0 - m);
    float e1 = has1 ? expf(v1 - m) : 0.f;
    float ssum = e0 + e1;
#pragma unroll
    for (int s = 1; s < 32; s <<= 1) ssum += __shfl_xor(ssum, s, 64);
    float inv = 1.f / ssum;
    smf[LGF + g * 60 + l] = e0 * inv;
    if (has1) smf[LGF + g * 60 + 32 + l] = e1 * inv;
  }
  __syncthreads();

  // ================= Phase 6: diff softmax per head h ======================
  {
    int h = t >> 6;
    int a = t & 63;
    float lam = smf[LAMF];
    float dlog = -1e30f;
    if (a < A_DIM) {
      float p0 = smf[LGF + (2 * h) * 60 + a];
      float p1 = smf[LGF + (2 * h + 1) * 60 + a];
      dlog = p0 - lam * p1;
    }
    float m = dlog;
#pragma unroll
    for (int s = 1; s < 64; s <<= 1) m = fmaxf(m, __shfl_xor(m, s, 64));
    float e = (a < A_DIM) ? expf(dlog - m) : 0.f;
    float ss = e;
#pragma unroll
    for (int s = 1; s < 64; s <<= 1) ss += __shfl_xor(ss, s, 64);
    if (a < A_DIM) smf[DPF + h * 60 + a] = e / ss;
  }
  __syncthreads();

  // ================= Phase 7: mean over heads ==============================
  if (t < A_DIM) {
    float r = 0.25f * (smf[DPF + t] + smf[DPF + 60 + t] +
                       smf[DPF + 120 + t] + smf[DPF + 180 + t]);
    out[(size_t)b * A_DIM + t] = r;
  }
}

extern "C" void kernel_launch(void* const* d_in, const int* in_sizes, int n_in,
                              void* d_out, int out_size, void* d_ws, size_t ws_size,
                              hipStream_t stream) {
  const float* x       = (const float*)d_in[0];
  const float* w_emb   = (const float*)d_in[1];
  const float* b_emb   = (const float*)d_in[2];
  const float* w_atlas = (const float*)d_in[3];
  const float* b_atlas = (const float*)d_in[4];
  const float* w_k     = (const float*)d_in[5];
  const float* qn_w    = (const float*)d_in[6];
  const float* qn_b    = (const float*)d_in[7];
  const float* kn_w    = (const float*)d_in[8];
  const float* kn_b    = (const float*)d_in[9];
  const float* lq1     = (const float*)d_in[10];
  const float* lk1     = (const float*)d_in[11];
  const float* lq2     = (const float*)d_in[12];
  const float* lk2     = (const float*)d_in[13];
  float* out = (float*)d_out;
  unsigned short* ws = (unsigned short*)d_ws;

  prep_weights<<<dim3(PREP_ELEMS / 256), dim3(256), 0, stream>>>(w_emb, w_atlas, w_k, ws);

  const int Bn = in_sizes[0] / (A_DIM * E_DIM);   // 8192
  atlas_fused<<<dim3(Bn), dim3(256), 0, stream>>>(
      x, ws, b_emb, b_atlas, qn_w, qn_b, kn_w, kn_b,
      lq1, lk1, lq2, lk2, out);
}

// Round 4
// 955.540 us; speedup vs baseline: 6.5512x; 2.1416x over previous
//
#include <hip/hip_runtime.h>
#include <math.h>

#define A_DIM 56
#define E_DIM 128

typedef short short8 __attribute__((ext_vector_type(8)));
typedef float floatx4 __attribute__((ext_vector_type(4)));

// ---------------- LDS layout (byte offsets, 16B-aligned) ----------------
#define XT_HI_B 0           // xT bf16 [134 rows=e+3][72 ushort pitch (ci)]
#define XT_LO_B 19296
#define H_HI_B  38592       // h bf16 [62 rows=a+3][136 ushort pitch (ei)]
#define H_LO_B  55456
#define KM_B    0           // kmat fp32 [56][132] overlays dead xT
#define XR_HI_B H_HI_B      // x_row bf16 [56][136 ushort pitch (e)] overlays dead h
#define XR_LO_B H_LO_B
#define Q_B     72320
#define QN_B    72832
#define LG_B    73344
#define DP_B    75264
#define LAM_B   76224
#define SMEM_B  76240

#define QF   (Q_B/4)
#define QNF  (QN_B/4)
#define LGF  (LG_B/4)
#define DPF  (DP_B/4)
#define LAMF (LAM_B/4)
#define KP2  132

// ---------------- workspace (ushort offsets) — fragment-ordered ----------
// W1: [tap7][kc2][nt4][lm16][lkg4][8]   a=nt*16+lm, ci=kc*32+lkg*8+j
#define W1H 0
#define W1L 28672
// W2: [tap7][kc4][mt8][lm16][lkg4][8]   eo=mt*16+lm, ei=kc*32+lkg*8+j
#define W2H 57344
#define W2L 172032
// WK: [kc4][mt8][lm16][lkg4][8]         o=mt*16+lm,  e=kc*32+lkg*8+j
#define WKH 286720
#define WKL 303104
#define PREP_ELEMS 159744   // 28672 + 114688 + 16384

__device__ __forceinline__ unsigned rne16(unsigned u) {
  return (u + 0x7FFFu + ((u >> 16) & 1u)) >> 16;
}
__device__ __forceinline__ unsigned pack_hi16(unsigned u0, unsigned u1) {
  return __builtin_amdgcn_perm(u1, u0, 0x07060302u);
}
__device__ __forceinline__ float silu_f(float v) { return v / (1.f + __expf(-v)); }

__global__ void prep_weights(const float* __restrict__ w_emb,
                             const float* __restrict__ w_atlas,
                             const float* __restrict__ w_k,
                             unsigned short* __restrict__ ws) {
  int idx = blockIdx.x * 256 + threadIdx.x;
  if (idx >= PREP_ELEMS) return;
  float v; int dst_hi, dst_lo;
  if (idx < 28672) {
    int tap = idx >> 12, kc = (idx >> 11) & 1, nt = (idx >> 9) & 3;
    int lm = (idx >> 5) & 15, lkg = (idx >> 3) & 3, jj = idx & 7;
    int a = nt * 16 + lm, ci = kc * 32 + lkg * 8 + jj;
    v = (a < A_DIM && ci < A_DIM) ? w_emb[(a * A_DIM + ci) * 7 + tap] : 0.f;
    dst_hi = W1H + idx; dst_lo = W1L + idx;
  } else if (idx < 143360) {
    int j = idx - 28672;
    int tap = j >> 14, kc = (j >> 12) & 3, mt = (j >> 9) & 7;
    int lm = (j >> 5) & 15, lkg = (j >> 3) & 3, jj = j & 7;
    int eo = mt * 16 + lm, ei = kc * 32 + lkg * 8 + jj;
    v = w_atlas[(eo * E_DIM + ei) * 7 + tap];
    dst_hi = W2H + j; dst_lo = W2L + j;
  } else {
    int j = idx - 143360;
    int kc = j >> 12, mt = (j >> 9) & 7;
    int lm = (j >> 5) & 15, lkg = (j >> 3) & 3, jj = j & 7;
    int o = mt * 16 + lm, e = kc * 32 + lkg * 8 + jj;
    v = w_k[o * E_DIM + e];
    dst_hi = WKH + j; dst_lo = WKL + j;
  }
  unsigned u = __float_as_uint(v);
  unsigned hi = rne16(u);
  float lof = v - __uint_as_float(hi << 16);
  unsigned lo = rne16(__float_as_uint(lof));
  ws[dst_hi] = (unsigned short)hi;
  ws[dst_lo] = (unsigned short)lo;
}

__global__ __launch_bounds__(256, 2)
void atlas_fused(const float* __restrict__ x,
                 const unsigned short* __restrict__ ws,
                 const float* __restrict__ b_emb, const float* __restrict__ b_atlas,
                 const float* __restrict__ qn_w,  const float* __restrict__ qn_b,
                 const float* __restrict__ kn_w,  const float* __restrict__ kn_b,
                 const float* __restrict__ lq1,   const float* __restrict__ lk1,
                 const float* __restrict__ lq2,   const float* __restrict__ lk2,
                 float* __restrict__ out)
{
  __shared__ __align__(16) unsigned char smem[SMEM_B];
  float* smf = (float*)smem;
  const int t = threadIdx.x;
  const int b = blockIdx.x;
  const int lane = t & 63;
  const int w = __builtin_amdgcn_readfirstlane(t >> 6);
  const int lm = lane & 15;
  const int lkg8 = (lane >> 4) * 8;      // k-run start within 32-chunk
  const int lr = (lane >> 4) * 4;        // C row base within tile

  const float* xb = x + (size_t)b * (A_DIM * E_DIM);

  // ================= Phase 0: init LDS, stage xT hi/lo, lambda =============
  {
    uint4 z4 = make_uint4(0, 0, 0, 0);
    for (int i = t; i < 2412; i += 256) ((uint4*)smem)[i] = z4;   // zero xT region
    for (int i = t; i < 816; i += 256) {   // zero h pad rows {0,1,2,59,60,61}
      int arr = i / 408, j = i - arr * 408;
      int r6 = j / 68, c = j - r6 * 68;
      int row = (r6 < 3) ? r6 : 56 + r6;
      *(unsigned*)(smem + (arr ? H_LO_B : H_HI_B) + row * 272 + c * 4) = 0u;
    }
    if (t == 0) {
      float s1 = 0.f, s2 = 0.f;
      for (int i = 0; i < 16; ++i) { s1 += lq1[i] * lk1[i]; s2 += lq2[i] * lk2[i]; }
      smf[LAMF] = expf(s1) - expf(s2) + 0.7f;
    }
  }
  __syncthreads();
  {
    unsigned short* xth = (unsigned short*)(smem + XT_HI_B);
    unsigned short* xtl = (unsigned short*)(smem + XT_LO_B);
    for (int i = t; i < 1792; i += 256) {       // 56 a * 32 float4
      int a = i >> 5, e4 = i & 31;
      float4 v = *(const float4*)(xb + a * 128 + e4 * 4);
      float f[4] = {v.x, v.y, v.z, v.w};
#pragma unroll
      for (int j = 0; j < 4; ++j) {
        int e = e4 * 4 + j;
        unsigned u = __float_as_uint(f[j]);
        xth[(e + 3) * 72 + a] = (unsigned short)(u >> 16);
        float lof = f[j] - __uint_as_float(u & 0xFFFF0000u);
        xtl[(e + 3) * 72 + a] = (unsigned short)(__float_as_uint(lof) >> 16);
      }
    }
  }
  __syncthreads();

  // ================= Phase 1: conv1 (C1^T[e][a]) ===========================
  // A[m=e][k=ci] = xT (LDS hi/lo) ; B[k=ci][n=a] = W1 (global hi/lo)
  {
    floatx4 acc[2][4];
#pragma unroll
    for (int nt = 0; nt < 4; ++nt) {
      int a = nt * 16 + lm;
      float be = (a < A_DIM) ? b_emb[a] : 0.f;
#pragma unroll
      for (int mt = 0; mt < 2; ++mt) {
        acc[mt][nt][0] = be; acc[mt][nt][1] = be;
        acc[mt][nt][2] = be; acc[mt][nt][3] = be;
      }
    }
    const unsigned short* xh = (const unsigned short*)(smem + XT_HI_B);
    const unsigned short* xl = (const unsigned short*)(smem + XT_LO_B);
#pragma unroll 1
    for (int tap = 0; tap < 7; ++tap) {
      int arow0 = (32 * w + lm + tap) * 72;
      int arow1 = arow0 + 16 * 72;
#pragma unroll
      for (int kc = 0; kc < 2; ++kc) {
        int ko = kc * 32 + lkg8;
        const unsigned short* fb = ws + ((tap * 2 + kc) * 4) * 512 + lm * 32 + lkg8;
        short8 bh0 = *(const short8*)(fb + W1H);
        short8 bh1 = *(const short8*)(fb + W1H + 512);
        short8 bh2 = *(const short8*)(fb + W1H + 1024);
        short8 bh3 = *(const short8*)(fb + W1H + 1536);
        short8 bl0 = *(const short8*)(fb + W1L);
        short8 bl1 = *(const short8*)(fb + W1L + 512);
        short8 bl2 = *(const short8*)(fb + W1L + 1024);
        short8 bl3 = *(const short8*)(fb + W1L + 1536);
        short8 ah0 = *(const short8*)(xh + arow0 + ko);
        short8 ah1 = *(const short8*)(xh + arow1 + ko);
        short8 al0 = *(const short8*)(xl + arow0 + ko);
        short8 al1 = *(const short8*)(xl + arow1 + ko);
        short8 bh[4] = {bh0, bh1, bh2, bh3};
        short8 bl[4] = {bl0, bl1, bl2, bl3};
#pragma unroll
        for (int nt = 0; nt < 4; ++nt) {
          acc[0][nt] = __builtin_amdgcn_mfma_f32_16x16x32_bf16(ah0, bh[nt], acc[0][nt], 0, 0, 0);
          acc[0][nt] = __builtin_amdgcn_mfma_f32_16x16x32_bf16(al0, bh[nt], acc[0][nt], 0, 0, 0);
          acc[0][nt] = __builtin_amdgcn_mfma_f32_16x16x32_bf16(ah0, bl[nt], acc[0][nt], 0, 0, 0);
          acc[1][nt] = __builtin_amdgcn_mfma_f32_16x16x32_bf16(ah1, bh[nt], acc[1][nt], 0, 0, 0);
          acc[1][nt] = __builtin_amdgcn_mfma_f32_16x16x32_bf16(al1, bh[nt], acc[1][nt], 0, 0, 0);
          acc[1][nt] = __builtin_amdgcn_mfma_f32_16x16x32_bf16(ah1, bl[nt], acc[1][nt], 0, 0, 0);
        }
      }
    }
    // epilogue: SiLU, split hi/lo, write h[a+3][e] (4 consecutive e per lane)
#pragma unroll
    for (int mt = 0; mt < 2; ++mt) {
      int e0 = 16 * (2 * w + mt) + lr;
#pragma unroll
      for (int nt = 0; nt < 4; ++nt) {
        int a = 16 * nt + lm;
        if (a < A_DIM) {
          float v0 = silu_f(acc[mt][nt][0]), v1 = silu_f(acc[mt][nt][1]);
          float v2 = silu_f(acc[mt][nt][2]), v3 = silu_f(acc[mt][nt][3]);
          unsigned u0 = __float_as_uint(v0), u1 = __float_as_uint(v1);
          unsigned u2 = __float_as_uint(v2), u3 = __float_as_uint(v3);
          float l0 = v0 - __uint_as_float(u0 & 0xFFFF0000u);
          float l1 = v1 - __uint_as_float(u1 & 0xFFFF0000u);
          float l2 = v2 - __uint_as_float(u2 & 0xFFFF0000u);
          float l3 = v3 - __uint_as_float(u3 & 0xFFFF0000u);
          int off = (a + 3) * 272 + e0 * 2;
          *(uint2*)(smem + H_HI_B + off) = make_uint2(pack_hi16(u0, u1), pack_hi16(u2, u3));
          *(uint2*)(smem + H_LO_B + off) =
              make_uint2(pack_hi16(__float_as_uint(l0), __float_as_uint(l1)),
                         pack_hi16(__float_as_uint(l2), __float_as_uint(l3)));
        }
      }
    }
  }
  __syncthreads();

  // ================= Phase 2: conv2 (C2[eo][a]) + mean over a -> q =========
  // A[m=eo][k=ei] = W2 (global hi/lo) ; B[k=ei][n=a] = h (LDS hi/lo)
  {
    floatx4 acc[2][4];
#pragma unroll
    for (int mt = 0; mt < 2; ++mt) {
      int eo0 = 16 * (2 * w + mt) + lr;
      float c0 = b_atlas[eo0], c1 = b_atlas[eo0 + 1];
      float c2 = b_atlas[eo0 + 2], c3 = b_atlas[eo0 + 3];
#pragma unroll
      for (int nt = 0; nt < 4; ++nt) {
        acc[mt][nt][0] = c0; acc[mt][nt][1] = c1;
        acc[mt][nt][2] = c2; acc[mt][nt][3] = c3;
      }
    }
    const unsigned char* hh = smem + H_HI_B;
    const unsigned char* hl = smem + H_LO_B;
#pragma unroll 1
    for (int tap = 0; tap < 7; ++tap) {
      int rofs[4];
#pragma unroll
      for (int nt = 0; nt < 4; ++nt) {
        int r = 16 * nt + lm + tap;
        rofs[nt] = ((r > 61) ? 61 : r) * 272;   // clamp touches only a>=56 (discarded)
      }
#pragma unroll
      for (int kc = 0; kc < 4; ++kc) {
        int kob = (kc * 32 + lkg8) * 2;
        const unsigned short* fb = ws + ((tap * 4 + kc) * 8 + 2 * w) * 512 + lm * 32 + lkg8;
        short8 ah0 = *(const short8*)(fb + W2H);
        short8 ah1 = *(const short8*)(fb + W2H + 512);
        short8 al0 = *(const short8*)(fb + W2L);
        short8 al1 = *(const short8*)(fb + W2L + 512);
        short8 bh[4], bl[4];
#pragma unroll
        for (int nt = 0; nt < 4; ++nt) {
          bh[nt] = *(const short8*)(hh + rofs[nt] + kob);
          bl[nt] = *(const short8*)(hl + rofs[nt] + kob);
        }
#pragma unroll
        for (int nt = 0; nt < 4; ++nt) {
          acc[0][nt] = __builtin_amdgcn_mfma_f32_16x16x32_bf16(ah0, bh[nt], acc[0][nt], 0, 0, 0);
          acc[0][nt] = __builtin_amdgcn_mfma_f32_16x16x32_bf16(al0, bh[nt], acc[0][nt], 0, 0, 0);
          acc[0][nt] = __builtin_amdgcn_mfma_f32_16x16x32_bf16(ah0, bl[nt], acc[0][nt], 0, 0, 0);
          acc[1][nt] = __builtin_amdgcn_mfma_f32_16x16x32_bf16(ah1, bh[nt], acc[1][nt], 0, 0, 0);
          acc[1][nt] = __builtin_amdgcn_mfma_f32_16x16x32_bf16(al1, bh[nt], acc[1][nt], 0, 0, 0);
          acc[1][nt] = __builtin_amdgcn_mfma_f32_16x16x32_bf16(ah1, bl[nt], acc[1][nt], 0, 0, 0);
        }
      }
    }
    // epilogue: SiLU, mask a<56, reduce over a, write q[eo]
#pragma unroll
    for (int mt = 0; mt < 2; ++mt) {
#pragma unroll
      for (int r = 0; r < 4; ++r) {
        float s = 0.f;
#pragma unroll
        for (int nt = 0; nt < 4; ++nt) {
          float v = silu_f(acc[mt][nt][r]);
          int a = 16 * nt + lm;
          s += (a < A_DIM) ? v : 0.f;
        }
        s += __shfl_xor(s, 1, 64);
        s += __shfl_xor(s, 2, 64);
        s += __shfl_xor(s, 4, 64);
        s += __shfl_xor(s, 8, 64);
        if (lm == 0) {
          int eo = 16 * (2 * w + mt) + lr + r;
          smf[QF + eo] = s * (1.f / 56.f);
        }
      }
    }
  }
  __syncthreads();

  // ====== Phase 3a: LN(q) (t<128) + re-stage x rows hi/lo into dead h ======
  if (t < 128) {
    float v = smf[QF + t];
    float s = v;
#pragma unroll
    for (int m = 1; m < 16; m <<= 1) s += __shfl_xor(s, m, 64);
    float mean = s * (1.f / 16.f);
    float d = v - mean;
    float s2 = d * d;
#pragma unroll
    for (int m = 1; m < 16; m <<= 1) s2 += __shfl_xor(s2, m, 64);
    float var = s2 * (1.f / 16.f);
    int dd = t & 15;
    float qn = d * rsqrtf(var + 1e-5f) * qn_w[dd] + qn_b[dd];
    smf[QNF + t] = qn * 0.25f;                 // SCALING = 16^-0.5
  }
  for (int i = t; i < 1792; i += 256) {        // x_row: [a][e] bf16 hi/lo
    int a = i >> 5, e4 = i & 31;
    float4 v = *(const float4*)(xb + a * 128 + e4 * 4);
    unsigned u0 = __float_as_uint(v.x), u1 = __float_as_uint(v.y);
    unsigned u2 = __float_as_uint(v.z), u3 = __float_as_uint(v.w);
    float l0 = v.x - __uint_as_float(u0 & 0xFFFF0000u);
    float l1 = v.y - __uint_as_float(u1 & 0xFFFF0000u);
    float l2 = v.z - __uint_as_float(u2 & 0xFFFF0000u);
    float l3 = v.w - __uint_as_float(u3 & 0xFFFF0000u);
    int off = a * 272 + e4 * 8;
    *(uint2*)(smem + XR_HI_B + off) = make_uint2(pack_hi16(u0, u1), pack_hi16(u2, u3));
    *(uint2*)(smem + XR_LO_B + off) =
        make_uint2(pack_hi16(__float_as_uint(l0), __float_as_uint(l1)),
                   pack_hi16(__float_as_uint(l2), __float_as_uint(l3)));
  }
  __syncthreads();

  // ================= Phase 3b: k-proj (C3^T[o][a]) -> kmat[a][o] ===========
  // A[m=o][k=e] = WK (global hi/lo) ; B[n=a][k=e] = x_row (LDS hi/lo)
  {
    floatx4 acc[2][4];
#pragma unroll
    for (int mt = 0; mt < 2; ++mt)
#pragma unroll
      for (int nt = 0; nt < 4; ++nt) {
        acc[mt][nt][0] = 0.f; acc[mt][nt][1] = 0.f;
        acc[mt][nt][2] = 0.f; acc[mt][nt][3] = 0.f;
      }
    const unsigned char* xrh = smem + XR_HI_B;
    const unsigned char* xrl = smem + XR_LO_B;
    int rofs[4];
#pragma unroll
    for (int nt = 0; nt < 4; ++nt) {
      int a = 16 * nt + lm;
      rofs[nt] = ((a > 55) ? 55 : a) * 272;
    }
#pragma unroll 1
    for (int kc = 0; kc < 4; ++kc) {
      int kob = (kc * 32 + lkg8) * 2;
      const unsigned short* fb = ws + (kc * 8 + 2 * w) * 512 + lm * 32 + lkg8;
      short8 ah0 = *(const short8*)(fb + WKH);
      short8 ah1 = *(const short8*)(fb + WKH + 512);
      short8 al0 = *(const short8*)(fb + WKL);
      short8 al1 = *(const short8*)(fb + WKL + 512);
      short8 bh[4], bl[4];
#pragma unroll
      for (int nt = 0; nt < 4; ++nt) {
        bh[nt] = *(const short8*)(xrh + rofs[nt] + kob);
        bl[nt] = *(const short8*)(xrl + rofs[nt] + kob);
      }
#pragma unroll
      for (int nt = 0; nt < 4; ++nt) {
        acc[0][nt] = __builtin_amdgcn_mfma_f32_16x16x32_bf16(ah0, bh[nt], acc[0][nt], 0, 0, 0);
        acc[0][nt] = __builtin_amdgcn_mfma_f32_16x16x32_bf16(al0, bh[nt], acc[0][nt], 0, 0, 0);
        acc[0][nt] = __builtin_amdgcn_mfma_f32_16x16x32_bf16(ah0, bl[nt], acc[0][nt], 0, 0, 0);
        acc[1][nt] = __builtin_amdgcn_mfma_f32_16x16x32_bf16(ah1, bh[nt], acc[1][nt], 0, 0, 0);
        acc[1][nt] = __builtin_amdgcn_mfma_f32_16x16x32_bf16(al1, bh[nt], acc[1][nt], 0, 0, 0);
        acc[1][nt] = __builtin_amdgcn_mfma_f32_16x16x32_bf16(ah1, bl[nt], acc[1][nt], 0, 0, 0);
      }
    }
#pragma unroll
    for (int mt = 0; mt < 2; ++mt) {
      int o0 = 16 * (2 * w + mt) + lr;
#pragma unroll
      for (int nt = 0; nt < 4; ++nt) {
        int a = 16 * nt + lm;
        if (a < A_DIM)
          *(floatx4*)&smf[(KM_B / 4) + a * KP2 + o0] = acc[mt][nt];
      }
    }
  }
  __syncthreads();

  // ================= Phase 4: layernorm(k) + logit = qn . kn ===============
  for (int r = 0; r < 2; ++r) {
    int task = t + r * 256;
    if (task < A_DIM * 8) {
      int a = task >> 3, h2 = task & 7;
      float kv[16];
      float s = 0.f;
#pragma unroll
      for (int d = 0; d < 16; ++d) { kv[d] = smf[(KM_B / 4) + a * KP2 + h2 * 16 + d]; s += kv[d]; }
      float mean = s * (1.f / 16.f);
      float s2 = 0.f;
#pragma unroll
      for (int d = 0; d < 16; ++d) { float dd = kv[d] - mean; s2 += dd * dd; }
      float rs = rsqrtf(s2 * (1.f / 16.f) + 1e-5f);
      float logit = 0.f;
#pragma unroll
      for (int d = 0; d < 16; ++d) {
        float kn = (kv[d] - mean) * rs * kn_w[d] + kn_b[d];
        logit += smf[QNF + h2 * 16 + d] * kn;
      }
      smf[LGF + h2 * 60 + a] = logit;
    }
  }
  __syncthreads();

  // ================= Phase 5: softmax over a per head2 =====================
  {
    int g = t >> 5;
    int l = t & 31;
    float v0 = smf[LGF + g * 60 + l];
    bool has1 = (l < A_DIM - 32);
    float v1 = has1 ? smf[LGF + g * 60 + 32 + l] : -1e30f;
    float m = fmaxf(v0, v1);
#pragma unroll
    for (int s = 1; s < 32; s <<= 1) m = fmaxf(m, __shfl_xor(m, s, 64));
    float e0 = expf(v0 - m);
    float e1 = has1 ? expf(v1 - m) : 0.f;
    float ssum = e0 + e1;
#pragma unroll
    for (int s = 1; s < 32; s <<= 1) ssum += __shfl_xor(ssum, s, 64);
    float inv = 1.f / ssum;
    smf[LGF + g * 60 + l] = e0 * inv;
    if (has1) smf[LGF + g * 60 + 32 + l] = e1 * inv;
  }
  __syncthreads();

  // ================= Phase 6: diff softmax per head h ======================
  {
    int h = t >> 6;
    int a = t & 63;
    float lam = smf[LAMF];
    float dlog = -1e30f;
    if (a < A_DIM) {
      float p0 = smf[LGF + (2 * h) * 60 + a];
      float p1 = smf[LGF + (2 * h + 1) * 60 + a];
      dlog = p0 - lam * p1;
    }
    float m = dlog;
#pragma unroll
    for (int s = 1; s < 64; s <<= 1) m = fmaxf(m, __shfl_xor(m, s, 64));
    float e = (a < A_DIM) ? expf(dlog - m) : 0.f;
    float ss = e;
#pragma unroll
    for (int s = 1; s < 64; s <<= 1) ss += __shfl_xor(ss, s, 64);
    if (a < A_DIM) smf[DPF + h * 60 + a] = e / ss;
  }
  __syncthreads();

  // ================= Phase 7: mean over heads ==============================
  if (t < A_DIM) {
    float r = 0.25f * (smf[DPF + t] + smf[DPF + 60 + t] +
                       smf[DPF + 120 + t] + smf[DPF + 180 + t]);
    out[(size_t)b * A_DIM + t] = r;
  }
}

extern "C" void kernel_launch(void* const* d_in, const int* in_sizes, int n_in,
                              void* d_out, int out_size, void* d_ws, size_t ws_size,
                              hipStream_t stream) {
  const float* x       = (const float*)d_in[0];
  const float* w_emb   = (const float*)d_in[1];
  const float* b_emb   = (const float*)d_in[2];
  const float* w_atlas = (const float*)d_in[3];
  const float* b_atlas = (const float*)d_in[4];
  const float* w_k     = (const float*)d_in[5];
  const float* qn_w    = (const float*)d_in[6];
  const float* qn_b    = (const float*)d_in[7];
  const float* kn_w    = (const float*)d_in[8];
  const float* kn_b    = (const float*)d_in[9];
  const float* lq1     = (const float*)d_in[10];
  const float* lk1     = (const float*)d_in[11];
  const float* lq2     = (const float*)d_in[12];
  const float* lk2     = (const float*)d_in[13];
  float* out = (float*)d_out;
  unsigned short* ws = (unsigned short*)d_ws;

  prep_weights<<<dim3((PREP_ELEMS + 255) / 256), dim3(256), 0, stream>>>(
      w_emb, w_atlas, w_k, ws);

  const int Bn = in_sizes[0] / (A_DIM * E_DIM);   // 8192
  atlas_fused<<<dim3(Bn), dim3(256), 0, stream>>>(
      x, ws, b_emb, b_atlas, qn_w, qn_b, kn_w, kn_b,
      lq1, lk1, lq2, lk2, out);
}